// Round 1
// baseline (143.334 us; speedup 1.0000x reference)
//
#include <hip/hip_runtime.h>

// SetConv RBF: B=4, NQ=4096, NC=4096, DC=2, DY=8, fp32.
// out[b,q,0:8] = sum_c w(q,c)*y[c] / (den+1e-8); out[b,q,8] = den = sum_c w(q,c)
// w = exp(-|xq-xc|^2 / (2*ls^2)), ls = exp(log_length_scale)

#define BB 4
#define NQ 4096
#define NC 4096
#define DY 8
#define SPLIT 8
#define QPB 256                 // queries per block (== blockDim.x)
#define CCHUNK (NC / SPLIT)     // 512 contexts per block

// Zero d_out (147456 floats = 36864 float4); harness poisons it with 0xAA.
__global__ __launch_bounds__(256) void setconv_zero(float4* __restrict__ out) {
    out[blockIdx.x * 256 + threadIdx.x] = make_float4(0.f, 0.f, 0.f, 0.f);
}

__global__ __launch_bounds__(256) void setconv_accum(
    const float* __restrict__ xq,   // (B,NQ,2)
    const float* __restrict__ xc,   // (B,NC,2)
    const float* __restrict__ yc,   // (B,NC,8)
    const float* __restrict__ lls,  // scalar log_length_scale
    float* __restrict__ out)        // (B,NQ,9) accumulator
{
    const int bid   = blockIdx.x;                   // 0..511
    const int split = bid & (SPLIT - 1);
    const int qblk  = (bid / SPLIT) & (NQ / QPB - 1);
    const int b     = bid / (SPLIT * (NQ / QPB));
    const int q     = qblk * QPB + threadIdx.x;

    // w = exp(-d2/(2*ls^2)) = exp2(d2 * negk), negk = -log2(e)/2 * exp(-2L)
    const float L    = lls[0];
    const float negk = -0.72134752044448f * exp2f(L * -2.8853900817779268f);

    const float2 qv = ((const float2*)xq)[b * NQ + q];
    const float qx = qv.x, qy = qv.y;

    float acc[DY];
#pragma unroll
    for (int j = 0; j < DY; ++j) acc[j] = 0.f;
    float den = 0.f;

    const float2* __restrict__ xcp = ((const float2*)xc) + (size_t)b * NC;
    const float4* __restrict__ ycp = ((const float4*)yc) + (size_t)b * NC * 2;

    const int c0 = split * CCHUNK;
#pragma unroll 4
    for (int c = c0; c < c0 + CCHUNK; ++c) {
        // c is wave-uniform -> scalar loads (s_load_dwordx2 / s_load_dwordx4)
        const float2 cv = xcp[c];
        const float4 y0 = ycp[2 * c + 0];
        const float4 y1 = ycp[2 * c + 1];
        const float dx = qx - cv.x;
        const float dy = qy - cv.y;
        const float d2 = fmaf(dy, dy, dx * dx);
        const float w  = exp2f(d2 * negk);   // v_exp_f32
        den += w;
        acc[0] = fmaf(w, y0.x, acc[0]);
        acc[1] = fmaf(w, y0.y, acc[1]);
        acc[2] = fmaf(w, y0.z, acc[2]);
        acc[3] = fmaf(w, y0.w, acc[3]);
        acc[4] = fmaf(w, y1.x, acc[4]);
        acc[5] = fmaf(w, y1.y, acc[5]);
        acc[6] = fmaf(w, y1.z, acc[6]);
        acc[7] = fmaf(w, y1.w, acc[7]);
    }

    float* o = out + (size_t)(b * NQ + q) * (DY + 1);
#pragma unroll
    for (int j = 0; j < DY; ++j) atomicAdd(o + j, acc[j]);
    atomicAdd(o + DY, den);
}

// Divide y sums by (density + 1e-8), in place. One thread per query.
__global__ __launch_bounds__(256) void setconv_norm(float* __restrict__ out) {
    const int q = blockIdx.x * 256 + threadIdx.x;   // 0..16383
    float* o = out + (size_t)q * (DY + 1);
    const float inv = 1.0f / (o[DY] + 1e-8f);
#pragma unroll
    for (int j = 0; j < DY; ++j) o[j] *= inv;
}

extern "C" void kernel_launch(void* const* d_in, const int* in_sizes, int n_in,
                              void* d_out, int out_size, void* d_ws, size_t ws_size,
                              hipStream_t stream) {
    const float* xq  = (const float*)d_in[0];  // (4,4096,2)
    const float* xc  = (const float*)d_in[1];  // (4,4096,2)
    const float* yc  = (const float*)d_in[2];  // (4,4096,8)
    const float* lls = (const float*)d_in[3];  // scalar
    float* out = (float*)d_out;                // (4,4096,9) = 147456 floats

    // 1) zero the accumulator/output (147456 floats / 1024 per block = 144)
    setconv_zero<<<144, 256, 0, stream>>>((float4*)out);
    // 2) partial accumulation: B * (NQ/QPB) * SPLIT = 4*16*8 = 512 blocks
    setconv_accum<<<BB * (NQ / QPB) * SPLIT, 256, 0, stream>>>(xq, xc, yc, lls, out);
    // 3) normalize: 16384 queries / 256 = 64 blocks
    setconv_norm<<<64, 256, 0, stream>>>(out);
}

// Round 2
// 93.178 us; speedup vs baseline: 1.5383x; 1.5383x over previous
//
#include <hip/hip_runtime.h>

// SetConv RBF: B=4, NQ=4096, NC=4096, DC=2, DY=8, fp32.
// out[b,q,0:8] = sum_c w(q,c)*y[c] / (den+1e-8); out[b,q,8] = den = sum_c w(q,c)
// w = exp(-|xq-xc|^2 / (2*ls^2)), ls = exp(log_length_scale)

#define BB 4
#define NQ 4096
#define NC 4096
#define DY 8
#define NBQ (BB * NQ)           // 16384 queries total

#if __has_builtin(__builtin_amdgcn_exp2f)
#define EXP2F(x) __builtin_amdgcn_exp2f(x)
#else
#define EXP2F(x) exp2f(x)
#endif

// ---------------- fast path: workspace partials, SPLIT=32 ----------------
#define SPLIT 32
#define CCH (NC / SPLIT)        // 128 contexts per block
#define WS_FLOATS ((size_t)(DY + 1) * SPLIT * NBQ)   // 4.7M floats = 18.9 MB

// ws layout: ws[j][split][bq], j in 0..8 (8 = density). All stores/loads
// dword-coalesced across lanes (lane-consecutive bq).
__global__ __launch_bounds__(256) void setconv_accum_ws(
    const float* __restrict__ xq, const float* __restrict__ xc,
    const float* __restrict__ yc, const float* __restrict__ lls,
    float* __restrict__ ws)
{
    const int bid   = blockIdx.x;              // 0..2047
    const int split = bid & (SPLIT - 1);
    const int qblk  = (bid >> 5) & (NQ / 256 - 1);
    const int b     = bid >> 9;
    const int q     = qblk * 256 + threadIdx.x;
    const int bq    = b * NQ + q;

    // w = exp(-d2/(2*ls^2)) = exp2(d2 * negk), negk = -log2(e)/2 * exp(-2L)
    const float L    = lls[0];
    const float negk = -0.72134752044448f * EXP2F(L * -2.8853900817779268f);

    const float2 qv = ((const float2*)xq)[bq];
    const float qx = qv.x, qy = qv.y;

    float acc[DY];
#pragma unroll
    for (int j = 0; j < DY; ++j) acc[j] = 0.f;
    float den = 0.f;

    const float2* __restrict__ xcp = ((const float2*)xc) + (size_t)b * NC;
    const float4* __restrict__ ycp = ((const float4*)yc) + (size_t)b * NC * 2;

    const int c0 = split * CCH;
#pragma unroll 8
    for (int c = c0; c < c0 + CCH; ++c) {
        // c is wave-uniform -> scalar (s_load) reads amortized over the wave
        const float2 cv = xcp[c];
        const float4 y0 = ycp[2 * c + 0];
        const float4 y1 = ycp[2 * c + 1];
        const float dx = qx - cv.x;
        const float dy = qy - cv.y;
        const float d2 = fmaf(dy, dy, dx * dx);
        const float w  = EXP2F(d2 * negk);     // v_exp_f32
        den += w;
        acc[0] = fmaf(w, y0.x, acc[0]);
        acc[1] = fmaf(w, y0.y, acc[1]);
        acc[2] = fmaf(w, y0.z, acc[2]);
        acc[3] = fmaf(w, y0.w, acc[3]);
        acc[4] = fmaf(w, y1.x, acc[4]);
        acc[5] = fmaf(w, y1.y, acc[5]);
        acc[6] = fmaf(w, y1.z, acc[6]);
        acc[7] = fmaf(w, y1.w, acc[7]);
    }

    float* w0 = ws + (size_t)split * NBQ + bq;
    const size_t JS = (size_t)SPLIT * NBQ;     // 524288
#pragma unroll
    for (int j = 0; j < DY; ++j) w0[j * JS] = acc[j];
    w0[DY * JS] = den;
}

// Reduce over SPLIT + normalize + write out. Block handles 64 queries with
// 256 threads (4 split-groups of 8). Grid = NBQ/64 = 256 blocks.
__global__ __launch_bounds__(256) void setconv_reduce(
    const float* __restrict__ ws, float* __restrict__ out)
{
    __shared__ float part[4][64][DY + 1];
    const int tid  = threadIdx.x;
    const int qi   = tid & 63;
    const int sg   = tid >> 6;                 // split-group 0..3
    const int base = blockIdx.x * 64;
    const int bq   = base + qi;
    const size_t JS = (size_t)SPLIT * NBQ;

#pragma unroll
    for (int j = 0; j < DY + 1; ++j) {
        float s = 0.f;
#pragma unroll
        for (int k = 0; k < SPLIT / 4; ++k) {
            const int split = sg * (SPLIT / 4) + k;
            s += ws[(size_t)j * JS + (size_t)split * NBQ + bq];  // coalesced
        }
        part[sg][qi][j] = s;
    }
    __syncthreads();

    // 576 output values per block, written coalesced: out[base*9 + it]
    for (int it = tid; it < 64 * (DY + 1); it += 256) {
        const int q2 = it / (DY + 1);
        const int j  = it - q2 * (DY + 1);
        const float den = part[0][q2][DY] + part[1][q2][DY] +
                          part[2][q2][DY] + part[3][q2][DY];
        float v;
        if (j == DY) {
            v = den;
        } else {
            const float s = part[0][q2][j] + part[1][q2][j] +
                            part[2][q2][j] + part[3][q2][j];
            v = s / (den + 1e-8f);
        }
        out[(size_t)base * (DY + 1) + it] = v;
    }
}

// ---------------- fallback path (round-1, known-good): atomics ----------------
#define FSPLIT 8
#define FCCH (NC / FSPLIT)

__global__ __launch_bounds__(256) void setconv_zero(float4* __restrict__ out) {
    out[blockIdx.x * 256 + threadIdx.x] = make_float4(0.f, 0.f, 0.f, 0.f);
}

__global__ __launch_bounds__(256) void setconv_accum_atomic(
    const float* __restrict__ xq, const float* __restrict__ xc,
    const float* __restrict__ yc, const float* __restrict__ lls,
    float* __restrict__ out)
{
    const int bid   = blockIdx.x;
    const int split = bid & (FSPLIT - 1);
    const int qblk  = (bid / FSPLIT) & (NQ / 256 - 1);
    const int b     = bid / (FSPLIT * (NQ / 256));
    const int q     = qblk * 256 + threadIdx.x;

    const float L    = lls[0];
    const float negk = -0.72134752044448f * EXP2F(L * -2.8853900817779268f);

    const float2 qv = ((const float2*)xq)[b * NQ + q];
    const float qx = qv.x, qy = qv.y;

    float acc[DY];
#pragma unroll
    for (int j = 0; j < DY; ++j) acc[j] = 0.f;
    float den = 0.f;

    const float2* __restrict__ xcp = ((const float2*)xc) + (size_t)b * NC;
    const float4* __restrict__ ycp = ((const float4*)yc) + (size_t)b * NC * 2;

    const int c0 = split * FCCH;
#pragma unroll 4
    for (int c = c0; c < c0 + FCCH; ++c) {
        const float2 cv = xcp[c];
        const float4 y0 = ycp[2 * c + 0];
        const float4 y1 = ycp[2 * c + 1];
        const float dx = qx - cv.x;
        const float dy = qy - cv.y;
        const float d2 = fmaf(dy, dy, dx * dx);
        const float w  = EXP2F(d2 * negk);
        den += w;
        acc[0] = fmaf(w, y0.x, acc[0]);
        acc[1] = fmaf(w, y0.y, acc[1]);
        acc[2] = fmaf(w, y0.z, acc[2]);
        acc[3] = fmaf(w, y0.w, acc[3]);
        acc[4] = fmaf(w, y1.x, acc[4]);
        acc[5] = fmaf(w, y1.y, acc[5]);
        acc[6] = fmaf(w, y1.z, acc[6]);
        acc[7] = fmaf(w, y1.w, acc[7]);
    }

    float* o = out + (size_t)(b * NQ + q) * (DY + 1);
#pragma unroll
    for (int j = 0; j < DY; ++j) atomicAdd(o + j, acc[j]);
    atomicAdd(o + DY, den);
}

__global__ __launch_bounds__(256) void setconv_norm(float* __restrict__ out) {
    const int q = blockIdx.x * 256 + threadIdx.x;
    float* o = out + (size_t)q * (DY + 1);
    const float inv = 1.0f / (o[DY] + 1e-8f);
#pragma unroll
    for (int j = 0; j < DY; ++j) o[j] *= inv;
}

extern "C" void kernel_launch(void* const* d_in, const int* in_sizes, int n_in,
                              void* d_out, int out_size, void* d_ws, size_t ws_size,
                              hipStream_t stream) {
    const float* xq  = (const float*)d_in[0];  // (4,4096,2)
    const float* xc  = (const float*)d_in[1];  // (4,4096,2)
    const float* yc  = (const float*)d_in[2];  // (4,4096,8)
    const float* lls = (const float*)d_in[3];  // scalar
    float* out = (float*)d_out;                // (4,4096,9)

    if (ws_size >= WS_FLOATS * sizeof(float)) {
        float* ws = (float*)d_ws;
        setconv_accum_ws<<<BB * (NQ / 256) * SPLIT, 256, 0, stream>>>(xq, xc, yc, lls, ws);
        setconv_reduce<<<NBQ / 64, 256, 0, stream>>>(ws, out);
    } else {
        setconv_zero<<<(NBQ * (DY + 1)) / 1024, 256, 0, stream>>>((float4*)out);
        setconv_accum_atomic<<<BB * (NQ / 256) * FSPLIT, 256, 0, stream>>>(xq, xc, yc, lls, out);
        setconv_norm<<<NBQ / 256, 256, 0, stream>>>(out);
    }
}